// Round 5
// baseline (1080.644 us; speedup 1.0000x reference)
//
#include <hip/hip_runtime.h>
#include <math.h>

// Volume dims (1,1,160,192,160) fp32
#define DD 160
#define HHH 192
#define WWW 160
constexpr int HW = HHH * WWW;          // 30720
constexpr int NV = DD * HHH * WWW;     // 4915200
constexpr int W4 = WWW / 4;            // 40
constexpr int HC = 3;                  // whsum5 H-chunk: 192/3 = 64 chunks -> 1600 blocks
constexpr int DC = 8;                  // dcc D-chunk: 160/8 = 20 chunks -> 2400 blocks
constexpr int SC = 5;                  // sobel_ring D-chunk: 160/5 = 32 chunks

__global__ void zero_acc(double* __restrict__ acc) {
    if (threadIdx.x < 3) acc[threadIdx.x] = 0.0;
}

__device__ __forceinline__ float4 ldg4(const float* __restrict__ p, int idx, bool ok) {
    float4 z = make_float4(0.f, 0.f, 0.f, 0.f);
    return ok ? *(const float4*)(p + idx) : z;
}

// ---- Laplacian, 4 outputs/thread -------------------------------------------
__global__ void lap4(const float* __restrict__ a, const float* __restrict__ b,
                     float* __restrict__ oa, float* __restrict__ ob) {
    int t = blockIdx.x * 256 + threadIdx.x;
    int w = (t % W4) * 4;
    int h = (t / W4) % HHH;
    int d = t / (W4 * HHH);
    int idx = (d * HHH + h) * WWW + w;
    bool dok0 = d > 0, dok1 = d < DD - 1, hok0 = h > 0, hok1 = h < HHH - 1;

#pragma unroll
    for (int s = 0; s < 2; s++) {
        const float* p = s ? b : a;
        float* o = s ? ob : oa;
        float4 c = *(const float4*)(p + idx);
        float m1 = (w > 0) ? p[idx - 1] : 0.f;
        float p4 = (w + 4 < WWW) ? p[idx + 4] : 0.f;
        float4 dm = ldg4(p, idx - HW, dok0);
        float4 dp = ldg4(p, idx + HW, dok1);
        float4 hm = ldg4(p, idx - WWW, hok0);
        float4 hp = ldg4(p, idx + WWW, hok1);
        float4 r;
        r.x = 6.f * c.x - (m1 + c.y + dm.x + dp.x + hm.x + hp.x);
        r.y = 6.f * c.y - (c.x + c.z + dm.y + dp.y + hm.y + hp.y);
        r.z = 6.f * c.z - (c.y + c.w + dm.z + dp.z + hm.z + hp.z);
        r.w = 6.f * c.w - (c.z + p4 + dm.w + dp.w + hm.w + hp.w);
        *(float4*)(o + idx) = r;
    }
}

// ---- Sobel magnitude, d-marching ring, 4 outputs/thread --------------------
__device__ __forceinline__ void sobel_slice(const float* __restrict__ p, int s, int h, int w,
                                            float a1[4], float a2[4], float a3[4]) {
#pragma unroll
    for (int k = 0; k < 4; k++) { a1[k] = 0.f; a2[k] = 0.f; a3[k] = 0.f; }
#pragma unroll
    for (int kh = -1; kh <= 1; kh++) {
        int h2 = h + kh;
        if ((unsigned)h2 < (unsigned)HHH) {
            int rb = (s * HHH + h2) * WWW + w;
            float4 cen = *(const float4*)(p + rb);
            float xm = (w > 0) ? p[rb - 1] : 0.f;
            float xp = (w + 4 < WWW) ? p[rb + 4] : 0.f;
            float xv[6] = {xm, cen.x, cen.y, cen.z, cen.w, xp};
            float smh = (kh == 0) ? 2.f : 1.f;
            float grh = (float)kh;
#pragma unroll
            for (int k = 0; k < 4; k++) {
                float gw = xv[k + 2] - xv[k];
                float pw = xv[k] + xv[k + 1] + xv[k + 2];
                float sw = pw + xv[k + 1];
                a1[k] += smh * gw;
                a2[k] += sw;
                a3[k] += grh * pw;
            }
        }
    }
}

__global__ void sobel_ring(const float* __restrict__ a, const float* __restrict__ b,
                           float* __restrict__ oa, float* __restrict__ ob) {
    int t = blockIdx.x * 256 + threadIdx.x;
    int w = (t % W4) * 4;
    int h = (t / W4) % HHH;
    int c = t / (W4 * HHH);
    int d0 = c * SC;

    float A1[2][3][4], A2[2][3][4], A3[2][3][4];
#pragma unroll
    for (int r = 0; r < 2; r++)
#pragma unroll
        for (int j = 0; j < 3; j++)
#pragma unroll
            for (int k = 0; k < 4; k++) { A1[r][j][k] = 0.f; A2[r][j][k] = 0.f; A3[r][j][k] = 0.f; }

#pragma unroll
    for (int i = 0; i < SC + 2; i++) {
        int s = d0 - 1 + i;
#pragma unroll
        for (int r = 0; r < 2; r++)
#pragma unroll
            for (int k = 0; k < 4; k++) {
                A1[r][0][k] = A1[r][1][k]; A2[r][0][k] = A2[r][1][k]; A3[r][0][k] = A3[r][1][k];
                A1[r][1][k] = A1[r][2][k]; A2[r][1][k] = A2[r][2][k]; A3[r][1][k] = A3[r][2][k];
            }
        if (s >= 0 && s < DD) {
            sobel_slice(a, s, h, w, A1[0][2], A2[0][2], A3[0][2]);
            sobel_slice(b, s, h, w, A1[1][2], A2[1][2], A3[1][2]);
        } else {
#pragma unroll
            for (int r = 0; r < 2; r++)
#pragma unroll
                for (int k = 0; k < 4; k++) { A1[r][2][k] = 0.f; A2[r][2][k] = 0.f; A3[r][2][k] = 0.f; }
        }
        if (i >= 2) {
            int d = s - 1;
            int idx = (d * HHH + h) * WWW + w;
            float4 ra, rb;
            float* pa = (float*)&ra;
            float* pb = (float*)&rb;
#pragma unroll
            for (int k = 0; k < 4; k++) {
                float gx = A1[0][0][k] + A1[0][1][k] + A1[0][2][k];
                float gy = A2[0][2][k] - A2[0][0][k];
                float gz = A3[0][0][k] + 2.f * A3[0][1][k] + A3[0][2][k];
                pa[k] = sqrtf(gx * gx + gy * gy + gz * gz);
                gx = A1[1][0][k] + A1[1][1][k] + A1[1][2][k];
                gy = A2[1][2][k] - A2[1][0][k];
                gz = A3[1][0][k] + 2.f * A3[1][1][k] + A3[1][2][k];
                pb[k] = sqrtf(gx * gx + gy * gy + gz * gz);
            }
            *(float4*)(oa + idx) = ra;
            *(float4*)(ob + idx) = rb;
        }
    }
}

// ---- Fused W+H box sums of 5 moments ---------------------------------------
// load12: fetch the 12-value tap span for one row of both arrays (6 f4 loads),
// zeros outside. Separate from compute so multiple rows' loads stay in flight.
__device__ __forceinline__ void load12(const float* __restrict__ a, const float* __restrict__ b,
                                       int rowbase, int w, bool ok,
                                       float x[12], float y[12]) {
    bool lo = ok && (w >= 4);
    bool hi = ok && (w + 7 < WWW);
    float4 x0 = ldg4(a, rowbase + w - 4, lo);
    float4 x1 = ldg4(a, rowbase + w, ok);
    float4 x2 = ldg4(a, rowbase + w + 4, hi);
    float4 y0 = ldg4(b, rowbase + w - 4, lo);
    float4 y1 = ldg4(b, rowbase + w, ok);
    float4 y2 = ldg4(b, rowbase + w + 4, hi);
    x[0] = x0.x; x[1] = x0.y; x[2] = x0.z; x[3] = x0.w;
    x[4] = x1.x; x[5] = x1.y; x[6] = x1.z; x[7] = x1.w;
    x[8] = x2.x; x[9] = x2.y; x[10] = x2.z; x[11] = x2.w;
    y[0] = y0.x; y[1] = y0.y; y[2] = y0.z; y[3] = y0.w;
    y[4] = y1.x; y[5] = y1.y; y[6] = y1.z; y[7] = y1.w;
    y[8] = y2.x; y[9] = y2.y; y[10] = y2.z; y[11] = y2.w;
}

__device__ __forceinline__ void q5_from(const float x[12], const float y[12], float q[5][4]) {
    float s0 = 0, s1 = 0, s2 = 0, s3 = 0, s4 = 0;
#pragma unroll
    for (int j = 0; j < 9; j++) {
        s0 += x[j]; s1 += y[j];
        s2 += x[j] * x[j]; s3 += y[j] * y[j]; s4 += x[j] * y[j];
    }
    q[0][0] = s0; q[1][0] = s1; q[2][0] = s2; q[3][0] = s3; q[4][0] = s4;
#pragma unroll
    for (int k = 1; k < 4; k++) {
        q[0][k] = q[0][k - 1] + x[k + 8] - x[k - 1];
        q[1][k] = q[1][k - 1] + y[k + 8] - y[k - 1];
        q[2][k] = q[2][k - 1] + x[k + 8] * x[k + 8] - x[k - 1] * x[k - 1];
        q[3][k] = q[3][k - 1] + y[k + 8] * y[k + 8] - y[k - 1] * y[k - 1];
        q[4][k] = q[4][k - 1] + x[k + 8] * y[k + 8] - x[k - 1] * y[k - 1];
    }
}

__global__ void whsum5(const float* __restrict__ a, const float* __restrict__ b,
                       float* __restrict__ t0, float* __restrict__ t1,
                       float* __restrict__ t2, float* __restrict__ t3,
                       float* __restrict__ t4) {
    int t = blockIdx.x * 256 + threadIdx.x;
    int w = (t % W4) * 4;
    int d = (t / W4) % DD;
    int c = t / (W4 * DD);
    int h0 = c * HC;

    float S[5][4] = {{0}};
    // warm-up rows h0-4 .. h0+4
    for (int j = 0; j < 9; j++) {
        int r = h0 - 4 + j;
        bool ok = (unsigned)r < (unsigned)HHH;
        float x[12], y[12], q[5][4];
        load12(a, b, (d * HHH + r) * WWW, w, ok, x, y);
        q5_from(x, y, q);
#pragma unroll
        for (int qq = 0; qq < 5; qq++)
#pragma unroll
            for (int k = 0; k < 4; k++) S[qq][k] += q[qq][k];
    }
    {
        int idx = (d * HHH + h0) * WWW + w;
        *(float4*)(t0 + idx) = make_float4(S[0][0], S[0][1], S[0][2], S[0][3]);
        *(float4*)(t1 + idx) = make_float4(S[1][0], S[1][1], S[1][2], S[1][3]);
        *(float4*)(t2 + idx) = make_float4(S[2][0], S[2][1], S[2][2], S[2][3]);
        *(float4*)(t3 + idx) = make_float4(S[3][0], S[3][1], S[3][2], S[3][3]);
        *(float4*)(t4 + idx) = make_float4(S[4][0], S[4][1], S[4][2], S[4][3]);
    }
#pragma unroll
    for (int h = h0 + 1; h < h0 + HC; h++) {
        int rin = h + 4, rout = h - 5;
        bool okin = rin < HHH, okout = rout >= 0;
        // batch both rows' loads (24 f4 in flight) before any compute
        float xi[12], yi[12], xo[12], yo[12];
        load12(a, b, (d * HHH + rin) * WWW, w, okin, xi, yi);
        load12(a, b, (d * HHH + rout) * WWW, w, okout, xo, yo);
        float qi[5][4], qo[5][4];
        q5_from(xi, yi, qi);
        q5_from(xo, yo, qo);
#pragma unroll
        for (int qq = 0; qq < 5; qq++)
#pragma unroll
            for (int k = 0; k < 4; k++) S[qq][k] += qi[qq][k] - qo[qq][k];
        int idx = (d * HHH + h) * WWW + w;
        *(float4*)(t0 + idx) = make_float4(S[0][0], S[0][1], S[0][2], S[0][3]);
        *(float4*)(t1 + idx) = make_float4(S[1][0], S[1][1], S[1][2], S[1][3]);
        *(float4*)(t2 + idx) = make_float4(S[2][0], S[2][1], S[2][2], S[2][3]);
        *(float4*)(t3 + idx) = make_float4(S[3][0], S[3][1], S[3][2], S[3][3]);
        *(float4*)(t4 + idx) = make_float4(S[4][0], S[4][1], S[4][2], S[4][3]);
    }
}

// ---- D box-sum + cc + reduction, scalar, sliding D window ------------------
__device__ __forceinline__ float cc1(float s0, float s1, float s2, float s3, float s4) {
    const float wsz = 729.0f;
    const float inv = 1.0f / 729.0f;
    float uI = s0 * inv;
    float uJ = s1 * inv;
    float cross = s4 - uJ * s0 - uI * s1 + uI * uJ * wsz;
    float Iv = s2 - 2.0f * uI * s0 + uI * uI * wsz;
    float Jv = s3 - 2.0f * uJ * s1 + uJ * uJ * wsz;
    return cross * cross / (Iv * Jv + 1e-5f);
}

__global__ void dcc(const float* __restrict__ t0, const float* __restrict__ t1,
                    const float* __restrict__ t2, const float* __restrict__ t3,
                    const float* __restrict__ t4, double* __restrict__ acc, int pair) {
    int t = blockIdx.x * 256 + threadIdx.x;
    int w = t % WWW;
    int h = (t / WWW) % HHH;
    int c = t / HW;
    int d0 = c * DC;

    float S0 = 0, S1 = 0, S2 = 0, S3 = 0, S4 = 0;
    for (int j = 0; j < 9; j++) {
        int r = d0 - 4 + j;
        if ((unsigned)r < (unsigned)DD) {
            int idx = (r * HHH + h) * WWW + w;
            S0 += t0[idx]; S1 += t1[idx]; S2 += t2[idx]; S3 += t3[idx]; S4 += t4[idx];
        }
    }
    float local = cc1(S0, S1, S2, S3, S4);
#pragma unroll
    for (int d = 1; d < DC; d++) {
        int rin = d0 + d + 4, rout = d0 + d - 5;
        bool okin = rin < DD, okout = rout >= 0;
        int iin = (rin * HHH + h) * WWW + w;
        int iout = (rout * HHH + h) * WWW + w;
        // batch all 10 loads before compute
        float a0 = okin ? t0[iin] : 0.f;
        float a1 = okin ? t1[iin] : 0.f;
        float a2 = okin ? t2[iin] : 0.f;
        float a3 = okin ? t3[iin] : 0.f;
        float a4 = okin ? t4[iin] : 0.f;
        float b0 = okout ? t0[iout] : 0.f;
        float b1 = okout ? t1[iout] : 0.f;
        float b2 = okout ? t2[iout] : 0.f;
        float b3 = okout ? t3[iout] : 0.f;
        float b4 = okout ? t4[iout] : 0.f;
        S0 += a0 - b0; S1 += a1 - b1; S2 += a2 - b2; S3 += a3 - b3; S4 += a4 - b4;
        local += cc1(S0, S1, S2, S3, S4);
    }

    for (int off = 32; off > 0; off >>= 1) local += __shfl_down(local, off);
    __shared__ float wsum_[4];
    if ((threadIdx.x & 63) == 0) wsum_[threadIdx.x >> 6] = local;
    __syncthreads();
    if (threadIdx.x == 0) {
        float s = wsum_[0] + wsum_[1] + wsum_[2] + wsum_[3];
        atomicAdd(&acc[pair], (double)s);
    }
}

__global__ void finalize_k(const double* __restrict__ acc, float* __restrict__ out) {
    if (threadIdx.x == 0) {
        double v = 0.8 * acc[0] + 0.1 * acc[1] + 0.1 * acc[2];
        out[0] = (float)(-v / (double)NV);
    }
}

extern "C" void kernel_launch(void* const* d_in, const int* in_sizes, int n_in,
                              void* d_out, int out_size, void* d_ws, size_t ws_size,
                              hipStream_t stream) {
    const float* yt = (const float*)d_in[0];
    const float* yp = (const float*)d_in[1];
    float* out = (float*)d_out;

    double* acc = (double*)d_ws;
    float* base = (float*)((char*)d_ws + 256);
    float* bufA = base;
    float* bufB = base + (size_t)NV;
    float* t0 = base + 2 * (size_t)NV;
    float* t1 = base + 3 * (size_t)NV;
    float* t2 = base + 4 * (size_t)NV;
    float* t3 = base + 5 * (size_t)NV;
    float* t4 = base + 6 * (size_t)NV;

    dim3 blk(256);
    dim3 grdE((NV / 4) / 256);                     // 4800 (lap4)
    dim3 grdS((W4 * HHH * (DD / SC)) / 256);       // 960  (sobel_ring)
    dim3 grdWH((W4 * DD * (HHH / HC)) / 256);      // 1600
    dim3 grdD((WWW * HHH * (DD / DC)) / 256);      // 2400

    hipLaunchKernelGGL(zero_acc, dim3(1), dim3(64), 0, stream, acc);

    // pair 0: raw inputs
    hipLaunchKernelGGL(whsum5, grdWH, blk, 0, stream, yt, yp, t0, t1, t2, t3, t4);
    hipLaunchKernelGGL(dcc, grdD, blk, 0, stream, t0, t1, t2, t3, t4, acc, 0);

    // pair 1: Laplacian
    hipLaunchKernelGGL(lap4, grdE, blk, 0, stream, yt, yp, bufA, bufB);
    hipLaunchKernelGGL(whsum5, grdWH, blk, 0, stream, bufA, bufB, t0, t1, t2, t3, t4);
    hipLaunchKernelGGL(dcc, grdD, blk, 0, stream, t0, t1, t2, t3, t4, acc, 1);

    // pair 2: Sobel magnitude
    hipLaunchKernelGGL(sobel_ring, grdS, blk, 0, stream, yt, yp, bufA, bufB);
    hipLaunchKernelGGL(whsum5, grdWH, blk, 0, stream, bufA, bufB, t0, t1, t2, t3, t4);
    hipLaunchKernelGGL(dcc, grdD, blk, 0, stream, t0, t1, t2, t3, t4, acc, 2);

    hipLaunchKernelGGL(finalize_k, dim3(1), dim3(1), 0, stream, acc, out);
}

// Round 6
// 511.018 us; speedup vs baseline: 2.1147x; 2.1147x over previous
//
#include <hip/hip_runtime.h>
#include <math.h>

// Volume dims (1,1,160,192,160) fp32
#define DD 160
#define HHH 192
#define WWW 160
constexpr int HW = HHH * WWW;          // 30720
constexpr int NV = DD * HHH * WWW;     // 4915200
constexpr int W4 = WWW / 4;            // 40
constexpr int HC = 4;                  // whsum5 H-chunk: 192/4 = 48 chunks -> 1200 blocks
constexpr int DC = 8;                  // dcc D-chunk: 160/8 = 20 chunks -> 2400 blocks
constexpr int SC = 5;                  // sobel_ring D-chunk: 160/5 = 32 chunks

__global__ void zero_acc(double* __restrict__ acc) {
    if (threadIdx.x < 3) acc[threadIdx.x] = 0.0;
}

__device__ __forceinline__ float4 ldg4(const float* __restrict__ p, int idx, bool ok) {
    float4 z = make_float4(0.f, 0.f, 0.f, 0.f);
    return ok ? *(const float4*)(p + idx) : z;
}

// ---- Laplacian, 4 outputs/thread -------------------------------------------
__global__ void lap4(const float* __restrict__ a, const float* __restrict__ b,
                     float* __restrict__ oa, float* __restrict__ ob) {
    int t = blockIdx.x * 256 + threadIdx.x;
    int w = (t % W4) * 4;
    int h = (t / W4) % HHH;
    int d = t / (W4 * HHH);
    int idx = (d * HHH + h) * WWW + w;
    bool dok0 = d > 0, dok1 = d < DD - 1, hok0 = h > 0, hok1 = h < HHH - 1;

#pragma unroll
    for (int s = 0; s < 2; s++) {
        const float* p = s ? b : a;
        float* o = s ? ob : oa;
        float4 c = *(const float4*)(p + idx);
        float m1 = (w > 0) ? p[idx - 1] : 0.f;
        float p4 = (w + 4 < WWW) ? p[idx + 4] : 0.f;
        float4 dm = ldg4(p, idx - HW, dok0);
        float4 dp = ldg4(p, idx + HW, dok1);
        float4 hm = ldg4(p, idx - WWW, hok0);
        float4 hp = ldg4(p, idx + WWW, hok1);
        float4 r;
        r.x = 6.f * c.x - (m1 + c.y + dm.x + dp.x + hm.x + hp.x);
        r.y = 6.f * c.y - (c.x + c.z + dm.y + dp.y + hm.y + hp.y);
        r.z = 6.f * c.z - (c.y + c.w + dm.z + dp.z + hm.z + hp.z);
        r.w = 6.f * c.w - (c.z + p4 + dm.w + dp.w + hm.w + hp.w);
        *(float4*)(o + idx) = r;
    }
}

// ---- Sobel magnitude, d-marching ring, 4 outputs/thread --------------------
__device__ __forceinline__ void sobel_slice(const float* __restrict__ p, int s, int h, int w,
                                            float a1[4], float a2[4], float a3[4]) {
#pragma unroll
    for (int k = 0; k < 4; k++) { a1[k] = 0.f; a2[k] = 0.f; a3[k] = 0.f; }
#pragma unroll
    for (int kh = -1; kh <= 1; kh++) {
        int h2 = h + kh;
        if ((unsigned)h2 < (unsigned)HHH) {
            int rb = (s * HHH + h2) * WWW + w;
            float4 cen = *(const float4*)(p + rb);
            float xm = (w > 0) ? p[rb - 1] : 0.f;
            float xp = (w + 4 < WWW) ? p[rb + 4] : 0.f;
            float xv[6] = {xm, cen.x, cen.y, cen.z, cen.w, xp};
            float smh = (kh == 0) ? 2.f : 1.f;
            float grh = (float)kh;
#pragma unroll
            for (int k = 0; k < 4; k++) {
                float gw = xv[k + 2] - xv[k];
                float pw = xv[k] + xv[k + 1] + xv[k + 2];
                float sw = pw + xv[k + 1];
                a1[k] += smh * gw;
                a2[k] += sw;
                a3[k] += grh * pw;
            }
        }
    }
}

__global__ void sobel_ring(const float* __restrict__ a, const float* __restrict__ b,
                           float* __restrict__ oa, float* __restrict__ ob) {
    int t = blockIdx.x * 256 + threadIdx.x;
    int w = (t % W4) * 4;
    int h = (t / W4) % HHH;
    int c = t / (W4 * HHH);
    int d0 = c * SC;

    float A1[2][3][4], A2[2][3][4], A3[2][3][4];
#pragma unroll
    for (int r = 0; r < 2; r++)
#pragma unroll
        for (int j = 0; j < 3; j++)
#pragma unroll
            for (int k = 0; k < 4; k++) { A1[r][j][k] = 0.f; A2[r][j][k] = 0.f; A3[r][j][k] = 0.f; }

#pragma unroll
    for (int i = 0; i < SC + 2; i++) {
        int s = d0 - 1 + i;
#pragma unroll
        for (int r = 0; r < 2; r++)
#pragma unroll
            for (int k = 0; k < 4; k++) {
                A1[r][0][k] = A1[r][1][k]; A2[r][0][k] = A2[r][1][k]; A3[r][0][k] = A3[r][1][k];
                A1[r][1][k] = A1[r][2][k]; A2[r][1][k] = A2[r][2][k]; A3[r][1][k] = A3[r][2][k];
            }
        if (s >= 0 && s < DD) {
            sobel_slice(a, s, h, w, A1[0][2], A2[0][2], A3[0][2]);
            sobel_slice(b, s, h, w, A1[1][2], A2[1][2], A3[1][2]);
        } else {
#pragma unroll
            for (int r = 0; r < 2; r++)
#pragma unroll
                for (int k = 0; k < 4; k++) { A1[r][2][k] = 0.f; A2[r][2][k] = 0.f; A3[r][2][k] = 0.f; }
        }
        if (i >= 2) {
            int d = s - 1;
            int idx = (d * HHH + h) * WWW + w;
            float4 ra, rb;
            float* pa = (float*)&ra;
            float* pb = (float*)&rb;
#pragma unroll
            for (int k = 0; k < 4; k++) {
                float gx = A1[0][0][k] + A1[0][1][k] + A1[0][2][k];
                float gy = A2[0][2][k] - A2[0][0][k];
                float gz = A3[0][0][k] + 2.f * A3[0][1][k] + A3[0][2][k];
                pa[k] = sqrtf(gx * gx + gy * gy + gz * gz);
                gx = A1[1][0][k] + A1[1][1][k] + A1[1][2][k];
                gy = A2[1][2][k] - A2[1][0][k];
                gz = A3[1][0][k] + 2.f * A3[1][1][k] + A3[1][2][k];
                pb[k] = sqrtf(gx * gx + gy * gy + gz * gz);
            }
            *(float4*)(oa + idx) = ra;
            *(float4*)(ob + idx) = rb;
        }
    }
}

// ---- Fused W+H box sums of 5 moments, 4 outputs/thread, sliding H window ----
// (R4 structure: sequential rin add then rout sub — low register pressure, no spill)
__device__ __forceinline__ void rowq5(const float* __restrict__ a, const float* __restrict__ b,
                                      int rowbase, int w, float q[5][4]) {
    bool lo = (w >= 4);
    bool hi = (w + 7 < WWW);
    float4 x0 = ldg4(a, rowbase + w - 4, lo);
    float4 x1 = *(const float4*)(a + rowbase + w);
    float4 x2 = ldg4(a, rowbase + w + 4, hi);
    float4 y0 = ldg4(b, rowbase + w - 4, lo);
    float4 y1 = *(const float4*)(b + rowbase + w);
    float4 y2 = ldg4(b, rowbase + w + 4, hi);
    float x[12] = {x0.x, x0.y, x0.z, x0.w, x1.x, x1.y, x1.z, x1.w, x2.x, x2.y, x2.z, x2.w};
    float y[12] = {y0.x, y0.y, y0.z, y0.w, y1.x, y1.y, y1.z, y1.w, y2.x, y2.y, y2.z, y2.w};
    float s0 = 0, s1 = 0, s2 = 0, s3 = 0, s4 = 0;
#pragma unroll
    for (int j = 0; j < 9; j++) {
        s0 += x[j]; s1 += y[j];
        s2 += x[j] * x[j]; s3 += y[j] * y[j]; s4 += x[j] * y[j];
    }
    q[0][0] = s0; q[1][0] = s1; q[2][0] = s2; q[3][0] = s3; q[4][0] = s4;
#pragma unroll
    for (int k = 1; k < 4; k++) {
        q[0][k] = q[0][k - 1] + x[k + 8] - x[k - 1];
        q[1][k] = q[1][k - 1] + y[k + 8] - y[k - 1];
        q[2][k] = q[2][k - 1] + x[k + 8] * x[k + 8] - x[k - 1] * x[k - 1];
        q[3][k] = q[3][k - 1] + y[k + 8] * y[k + 8] - y[k - 1] * y[k - 1];
        q[4][k] = q[4][k - 1] + x[k + 8] * y[k + 8] - x[k - 1] * y[k - 1];
    }
}

__global__ void whsum5(const float* __restrict__ a, const float* __restrict__ b,
                       float* __restrict__ t0, float* __restrict__ t1,
                       float* __restrict__ t2, float* __restrict__ t3,
                       float* __restrict__ t4) {
    int t = blockIdx.x * 256 + threadIdx.x;
    int w = (t % W4) * 4;
    int d = (t / W4) % DD;
    int c = t / (W4 * DD);
    int h0 = c * HC;

    float S[5][4] = {{0}};
    for (int j = 0; j < 9; j++) {
        int r = h0 - 4 + j;
        if ((unsigned)r < (unsigned)HHH) {
            float q[5][4];
            rowq5(a, b, (d * HHH + r) * WWW, w, q);
#pragma unroll
            for (int qq = 0; qq < 5; qq++)
#pragma unroll
                for (int k = 0; k < 4; k++) S[qq][k] += q[qq][k];
        }
    }
    {
        int idx = (d * HHH + h0) * WWW + w;
        *(float4*)(t0 + idx) = make_float4(S[0][0], S[0][1], S[0][2], S[0][3]);
        *(float4*)(t1 + idx) = make_float4(S[1][0], S[1][1], S[1][2], S[1][3]);
        *(float4*)(t2 + idx) = make_float4(S[2][0], S[2][1], S[2][2], S[2][3]);
        *(float4*)(t3 + idx) = make_float4(S[3][0], S[3][1], S[3][2], S[3][3]);
        *(float4*)(t4 + idx) = make_float4(S[4][0], S[4][1], S[4][2], S[4][3]);
    }
    for (int h = h0 + 1; h < h0 + HC; h++) {
        int rin = h + 4, rout = h - 5;
        if (rin < HHH) {
            float q[5][4];
            rowq5(a, b, (d * HHH + rin) * WWW, w, q);
#pragma unroll
            for (int qq = 0; qq < 5; qq++)
#pragma unroll
                for (int k = 0; k < 4; k++) S[qq][k] += q[qq][k];
        }
        if (rout >= 0) {
            float q[5][4];
            rowq5(a, b, (d * HHH + rout) * WWW, w, q);
#pragma unroll
            for (int qq = 0; qq < 5; qq++)
#pragma unroll
                for (int k = 0; k < 4; k++) S[qq][k] -= q[qq][k];
        }
        int idx = (d * HHH + h) * WWW + w;
        *(float4*)(t0 + idx) = make_float4(S[0][0], S[0][1], S[0][2], S[0][3]);
        *(float4*)(t1 + idx) = make_float4(S[1][0], S[1][1], S[1][2], S[1][3]);
        *(float4*)(t2 + idx) = make_float4(S[2][0], S[2][1], S[2][2], S[2][3]);
        *(float4*)(t3 + idx) = make_float4(S[3][0], S[3][1], S[3][2], S[3][3]);
        *(float4*)(t4 + idx) = make_float4(S[4][0], S[4][1], S[4][2], S[4][3]);
    }
}

// ---- D box-sum + cc + reduction, scalar, sliding D window ------------------
__device__ __forceinline__ float cc1(float s0, float s1, float s2, float s3, float s4) {
    const float wsz = 729.0f;
    const float inv = 1.0f / 729.0f;
    float uI = s0 * inv;
    float uJ = s1 * inv;
    float cross = s4 - uJ * s0 - uI * s1 + uI * uJ * wsz;
    float Iv = s2 - 2.0f * uI * s0 + uI * uI * wsz;
    float Jv = s3 - 2.0f * uJ * s1 + uJ * uJ * wsz;
    return cross * cross / (Iv * Jv + 1e-5f);
}

__global__ void dcc(const float* __restrict__ t0, const float* __restrict__ t1,
                    const float* __restrict__ t2, const float* __restrict__ t3,
                    const float* __restrict__ t4, double* __restrict__ acc, int pair) {
    int t = blockIdx.x * 256 + threadIdx.x;
    int w = t % WWW;
    int h = (t / WWW) % HHH;
    int c = t / HW;
    int d0 = c * DC;

    float S0 = 0, S1 = 0, S2 = 0, S3 = 0, S4 = 0;
    for (int j = 0; j < 9; j++) {
        int r = d0 - 4 + j;
        if ((unsigned)r < (unsigned)DD) {
            int idx = (r * HHH + h) * WWW + w;
            S0 += t0[idx]; S1 += t1[idx]; S2 += t2[idx]; S3 += t3[idx]; S4 += t4[idx];
        }
    }
    float local = cc1(S0, S1, S2, S3, S4);
#pragma unroll
    for (int d = 1; d < DC; d++) {
        int rin = d0 + d + 4, rout = d0 + d - 5;
        bool okin = rin < DD, okout = rout >= 0;
        int iin = (rin * HHH + h) * WWW + w;
        int iout = (rout * HHH + h) * WWW + w;
        float a0 = okin ? t0[iin] : 0.f;
        float a1 = okin ? t1[iin] : 0.f;
        float a2 = okin ? t2[iin] : 0.f;
        float a3 = okin ? t3[iin] : 0.f;
        float a4 = okin ? t4[iin] : 0.f;
        float b0 = okout ? t0[iout] : 0.f;
        float b1 = okout ? t1[iout] : 0.f;
        float b2 = okout ? t2[iout] : 0.f;
        float b3 = okout ? t3[iout] : 0.f;
        float b4 = okout ? t4[iout] : 0.f;
        S0 += a0 - b0; S1 += a1 - b1; S2 += a2 - b2; S3 += a3 - b3; S4 += a4 - b4;
        local += cc1(S0, S1, S2, S3, S4);
    }

    for (int off = 32; off > 0; off >>= 1) local += __shfl_down(local, off);
    __shared__ float wsum_[4];
    if ((threadIdx.x & 63) == 0) wsum_[threadIdx.x >> 6] = local;
    __syncthreads();
    if (threadIdx.x == 0) {
        float s = wsum_[0] + wsum_[1] + wsum_[2] + wsum_[3];
        atomicAdd(&acc[pair], (double)s);
    }
}

__global__ void finalize_k(const double* __restrict__ acc, float* __restrict__ out) {
    if (threadIdx.x == 0) {
        double v = 0.8 * acc[0] + 0.1 * acc[1] + 0.1 * acc[2];
        out[0] = (float)(-v / (double)NV);
    }
}

extern "C" void kernel_launch(void* const* d_in, const int* in_sizes, int n_in,
                              void* d_out, int out_size, void* d_ws, size_t ws_size,
                              hipStream_t stream) {
    const float* yt = (const float*)d_in[0];
    const float* yp = (const float*)d_in[1];
    float* out = (float*)d_out;

    double* acc = (double*)d_ws;
    float* base = (float*)((char*)d_ws + 256);
    float* bufA = base;
    float* bufB = base + (size_t)NV;
    float* t0 = base + 2 * (size_t)NV;
    float* t1 = base + 3 * (size_t)NV;
    float* t2 = base + 4 * (size_t)NV;
    float* t3 = base + 5 * (size_t)NV;
    float* t4 = base + 6 * (size_t)NV;

    dim3 blk(256);
    dim3 grdE((NV / 4) / 256);                     // 4800 (lap4)
    dim3 grdS((W4 * HHH * (DD / SC)) / 256);       // 960  (sobel_ring)
    dim3 grdWH((W4 * DD * (HHH / HC)) / 256);      // 1200
    dim3 grdD((WWW * HHH * (DD / DC)) / 256);      // 2400

    hipLaunchKernelGGL(zero_acc, dim3(1), dim3(64), 0, stream, acc);

    // pair 0: raw inputs
    hipLaunchKernelGGL(whsum5, grdWH, blk, 0, stream, yt, yp, t0, t1, t2, t3, t4);
    hipLaunchKernelGGL(dcc, grdD, blk, 0, stream, t0, t1, t2, t3, t4, acc, 0);

    // pair 1: Laplacian
    hipLaunchKernelGGL(lap4, grdE, blk, 0, stream, yt, yp, bufA, bufB);
    hipLaunchKernelGGL(whsum5, grdWH, blk, 0, stream, bufA, bufB, t0, t1, t2, t3, t4);
    hipLaunchKernelGGL(dcc, grdD, blk, 0, stream, t0, t1, t2, t3, t4, acc, 1);

    // pair 2: Sobel magnitude
    hipLaunchKernelGGL(sobel_ring, grdS, blk, 0, stream, yt, yp, bufA, bufB);
    hipLaunchKernelGGL(whsum5, grdWH, blk, 0, stream, bufA, bufB, t0, t1, t2, t3, t4);
    hipLaunchKernelGGL(dcc, grdD, blk, 0, stream, t0, t1, t2, t3, t4, acc, 2);

    hipLaunchKernelGGL(finalize_k, dim3(1), dim3(1), 0, stream, acc, out);
}